// Round 16
// baseline (353.033 us; speedup 1.0000x reference)
//
#include <hip/hip_runtime.h>
#include <hip/hip_bf16.h>

// Sizes fixed by the reference problem.
#define B_N   4096
#define D_N   1024
#define P_N   64
#define C0_N  16
#define C1_N  32
#define NC_N  48    // C0 + C1 concatenated

// parent GEMM K-split
#define KC1   16
#define DKC1  64
#define L1S   68     // 64+4: 16B-aligned rows; rows 16 apart -> 2-way bank alias (free)

// child GEMM K-split (r16: KC2=16 occupancy + r15 line-aligned writes)
#define KC2   16
#define DKC2  64
#define L2S   68     // same bank math as L1S
#define PCH   64     // part2 chunk padded 48 -> 64 floats (256B line-aligned,
                     // single-writer). r14 lesson: 192B chunks shared lines
                     // across 16 writer blocks/XCDs -> RMW + L2 ping-pong
                     // = 30-60x HBM amplification (FETCH 335MB/WRITE 427MB).

// Tie physics: fp32 softmax probs can only tie when the true logit gap is
// <~2e-7 (exp ulp 6e-8 near 1.0; prob ulp 1.9e-9 x s~64 = 1.2e-7; exp
// rounding +-6e-8). Our fp32 gap estimate is accurate to ~1e-9. tau=1e-6
// gives 5x margin and flags only ~15-30 rows total.
#define GAP_TAU 1e-6f
#define NEG_INF (-3.402823466e38f)

// NOTE (r10-r15 lessons): no grid.sync (~100us each); no per-block device
// fences (L2 writeback storm, +180us); no low-block-count kernels (64
// blocks = 2% occupancy, 87us); all global write chunks 256B-aligned and
// single-writer. Hand-off at kernel boundaries; every kernel >= ~500 blocks.

// ===========================================================================
// A: parent-logit partials (proven since r9). Grid (64 tiles, 16 kc) = 1024
// blocks, 4/CU. Partials [row][kc][p]: 256B-aligned chunks (no sharing).
// Block (0,0) zeroes counts.
// ===========================================================================
__global__ __launch_bounds__(256, 4)
void hc_parent_partial(const float* __restrict__ x,
                       const float* __restrict__ pw,
                       float* __restrict__ partials,
                       int* __restrict__ counts) {
    __shared__ float xs[64 * L1S];
    __shared__ float ws[P_N * L1S];
    const int tid = threadIdx.x;
    if (blockIdx.x == 0 && blockIdx.y == 0 && tid < P_N) counts[tid] = 0;

    const int r0 = blockIdx.x * 64;
    const int d0 = blockIdx.y * DKC1;

    #pragma unroll
    for (int k = 0; k < 4; ++k) {        // x: 64 rows x 64 floats
        const int f = tid + 256 * k, r = f >> 4, dp = (f & 15) * 4;
        *(float4*)&xs[r * L1S + dp] =
            *(const float4*)&x[(size_t)(r0 + r) * D_N + d0 + dp];
    }
    #pragma unroll
    for (int k = 0; k < 4; ++k) {        // pw chunk: 64 rows x 64 floats
        const int f = tid + 256 * k, r = f >> 4, dp = (f & 15) * 4;
        *(float4*)&ws[r * L1S + dp] =
            *(const float4*)&pw[(size_t)r * D_N + d0 + dp];
    }
    __syncthreads();

    const int pt = tid & 15;
    const int rt = tid >> 4;
    float acc[4][4] = {};                // [i: parent][j: row]
    #pragma unroll
    for (int d = 0; d < DKC1; d += 4) {
        float4 w4[4], x4[4];
        #pragma unroll
        for (int i = 0; i < 4; ++i)
            w4[i] = *(const float4*)&ws[(pt + 16 * i) * L1S + d];
        #pragma unroll
        for (int j = 0; j < 4; ++j)
            x4[j] = *(const float4*)&xs[(rt + 16 * j) * L1S + d];
        #pragma unroll
        for (int i = 0; i < 4; ++i)
            #pragma unroll
            for (int j = 0; j < 4; ++j) {
                acc[i][j] += w4[i].x * x4[j].x;
                acc[i][j] += w4[i].y * x4[j].y;
                acc[i][j] += w4[i].z * x4[j].z;
                acc[i][j] += w4[i].w * x4[j].w;
            }
    }
    const int kcb = blockIdx.y;
    #pragma unroll
    for (int j = 0; j < 4; ++j) {
        const size_t rbase =
            (size_t)(r0 + rt + 16 * j) * (KC1 * P_N) + (size_t)kcb * P_N;
        #pragma unroll
        for (int i = 0; i < 4; ++i)
            partials[rbase + pt + 16 * i] = acc[i][j];
    }
}

// ===========================================================================
// B: route + block-local cooperative f64 fixup (proven r13). Block = 4 rows
// (wave = one row's 64 parents). Fast path: reduce + bias -> logits, top-2,
// bin. Near-ties -> LDS queue; then the whole block cooperatively emulates
// the reference's fp32 softmax in f64 (exp quantization near 1.0 ties
// near-equal logits; argmax takes the FIRST tied index). ~26/1024 blocks
// take the slow path.
// ===========================================================================
__global__ __launch_bounds__(256, 6)
void hc_parent_route(const float* __restrict__ partials,
                     const float* __restrict__ pb,
                     const float* __restrict__ x,
                     const float* __restrict__ pw,
                     float* __restrict__ out_logits,
                     int* __restrict__ counts,
                     int* __restrict__ lists,
                     int* __restrict__ pclass) {
    __shared__ double ld[P_N];
    __shared__ int    sq[8];
    __shared__ int    sqn;

    const int tid = threadIdx.x;
    const int p   = tid & 63;
    const int w   = tid >> 6;
    const int row = blockIdx.x * 4 + w;

    if (tid == 0) sqn = 0;

    // ---- fast path ----
    const float* prow = &partials[(size_t)row * (KC1 * P_N)];
    float lv[KC1];
    #pragma unroll
    for (int kc = 0; kc < KC1; ++kc) lv[kc] = prow[kc * P_N + p];
    float l = pb[p];
    #pragma unroll
    for (int kc = 0; kc < KC1; ++kc) l += lv[kc];

    out_logits[(size_t)row * P_N + p] = l;

    float m1 = l; int i1 = p; float m2 = NEG_INF;
    #pragma unroll
    for (int off = 32; off > 0; off >>= 1) {
        const float om1 = __shfl_xor(m1, off);
        const int   oi1 = __shfl_xor(i1, off);
        const float om2 = __shfl_xor(m2, off);
        if (om1 > m1 || (om1 == m1 && oi1 < i1)) {
            m2 = fmaxf(m1, om2); m1 = om1; i1 = oi1;
        } else m2 = fmaxf(m2, om1);
    }
    if (p == 0) {
        if (m1 - m2 > GAP_TAU) {
            const int pos = atomicAdd(&counts[i1], 1);
            lists[i1 * B_N + pos] = row;
            pclass[row] = i1;
        } else {
            const int q = atomicAdd(&sqn, 1);
            sq[q] = row;
        }
    }
    __syncthreads();

    const int nq = sqn;
    if (nq == 0) return;    // uniform: all threads past the barrier

    // ---- block-cooperative slow path (~26 blocks total take this) ----
    for (int qi = 0; qi < nq; ++qi) {
        const int srow = sq[qi];
        const float* xr = &x[(size_t)srow * D_N + p * 16];
        float4 xv[4];
        #pragma unroll
        for (int k = 0; k < 4; ++k) xv[k] = *(const float4*)&xr[k * 4];

        #pragma unroll 2
        for (int pass = 0; pass < 16; ++pass) {
            const int pp = w * 16 + pass;
            const float* wr = &pw[(size_t)pp * D_N + p * 16];
            double a0 = 0.0, a1 = 0.0, a2 = 0.0, a3 = 0.0;
            #pragma unroll
            for (int k = 0; k < 4; ++k) {
                const float4 wv = *(const float4*)&wr[k * 4];
                a0 = fma((double)wv.x, (double)xv[k].x, a0);
                a1 = fma((double)wv.y, (double)xv[k].y, a1);
                a2 = fma((double)wv.z, (double)xv[k].z, a2);
                a3 = fma((double)wv.w, (double)xv[k].w, a3);
            }
            double a = (a0 + a1) + (a2 + a3);
            #pragma unroll
            for (int off = 32; off > 0; off >>= 1) a += __shfl_xor(a, off);
            if (p == 0) ld[pp] = a;
        }
        __syncthreads();

        if (w == 0) {
            const double accv = (double)pb[p] + ld[p];
            const float  l32  = (float)accv;
            float m = l32;
            #pragma unroll
            for (int off = 32; off > 0; off >>= 1)
                m = fmaxf(m, __shfl_xor(m, off));
            const float e = (float)exp((double)(l32 - m));  // correctly-rounded
            double es = (double)e;
            #pragma unroll
            for (int off = 32; off > 0; off >>= 1) es += __shfl_xor(es, off);
            es = __shfl(es, 0);
            const float s    = (float)es;
            const float prob = e / s;    // IEEE f32 divide: ties survive
            float pm = prob; int pi = p;
            #pragma unroll
            for (int off = 32; off > 0; off >>= 1) {
                const float opm = __shfl_xor(pm, off);
                const int   opi = __shfl_xor(pi, off);
                if (opm > pm || (opm == pm && opi < pi)) { pm = opm; pi = opi; }
            }
            if (p == 0) {
                const int pos = atomicAdd(&counts[pi], 1);
                lists[pi * B_N + pos] = srow;
                pclass[srow] = pi;
            }
        }
        __syncthreads();
    }
}

// ===========================================================================
// C: child-GEMM partials. r16: KC2=16/DKC2=64 (LDS 30.7KB -> 5 blocks/CU,
// ~1040 active blocks, 28KB staging/block) + r15's line-aligned part2.
// Grid (64 classes, 16 kc, 4 tile-slots); ghost slots exit immediately.
// part2 [row][kc16][PCH=64]: 256B chunk, 1 full line pair, single writer.
// ===========================================================================
__global__ __launch_bounds__(256, 5)
void hc_child_partial(const float* __restrict__ x,
                      const float* __restrict__ w0,
                      const float* __restrict__ w1,
                      const int* __restrict__ counts,
                      const int* __restrict__ lists,
                      float* __restrict__ part2) {
    const int c  = blockIdx.x;
    const int kc = blockIdx.y;
    const int n  = counts[c];
    const int t0 = blockIdx.z * 64;
    if (t0 >= n) return;
    const int m  = min(64, n - t0);
    const int d0 = kc * DKC2;

    __shared__ int   rl[64];
    __shared__ float xs[64 * L2S];
    __shared__ float ws[NC_N * L2S];

    const int tid = threadIdx.x;
    if (tid < 64)
        rl[tid] = lists[c * B_N + t0 + (tid < m ? tid : 0)];

    // stage class's 48 child-weight rows: 48 x 64 floats = 768 float4
    #pragma unroll
    for (int k = 0; k < 3; ++k) {
        const int f = tid + 256 * k, j = f >> 4, dp = (f & 15) * 4;
        const float* src = (j < C0_N)
            ? &w0[((size_t)c * C0_N + j) * D_N + d0 + dp]
            : &w1[((size_t)c * C1_N + (j - C0_N)) * D_N + d0 + dp];
        *(float4*)&ws[j * L2S + dp] = *(const float4*)src;
    }
    __syncthreads();   // rl visible
    // stage gathered x rows: 64 x 64 floats = 1024 float4
    #pragma unroll
    for (int k = 0; k < 4; ++k) {
        const int f = tid + 256 * k, r = f >> 4, dp = (f & 15) * 4;
        *(float4*)&xs[r * L2S + dp] =
            *(const float4*)&x[(size_t)rl[r] * D_N + d0 + dp];
    }
    __syncthreads();

    const int jt = tid & 15;
    const int rt = tid >> 4;

    float acc[3][4] = {};                // [i: output][j: row]
    #pragma unroll
    for (int d = 0; d < DKC2; d += 4) {
        float4 w4[3], x4[4];
        #pragma unroll
        for (int i = 0; i < 3; ++i)
            w4[i] = *(const float4*)&ws[(jt + 16 * i) * L2S + d];
        #pragma unroll
        for (int j = 0; j < 4; ++j)
            x4[j] = *(const float4*)&xs[(rt + 16 * j) * L2S + d];
        #pragma unroll
        for (int i = 0; i < 3; ++i)
            #pragma unroll
            for (int j = 0; j < 4; ++j) {
                acc[i][j] += w4[i].x * x4[j].x;
                acc[i][j] += w4[i].y * x4[j].y;
                acc[i][j] += w4[i].z * x4[j].z;
                acc[i][j] += w4[i].w * x4[j].w;
            }
    }

    #pragma unroll
    for (int j = 0; j < 4; ++j) {
        const int rr = rt + 16 * j;
        if (rr < m) {
            const size_t rbase =
                (size_t)rl[rr] * (KC2 * PCH) + (size_t)kc * PCH;
            #pragma unroll
            for (int i = 0; i < 4; ++i)   // i==3 writes padding (completes lines)
                part2[rbase + jt + 16 * i] = (i < 3) ? acc[i][j] : 0.0f;
        }
    }
}

// ===========================================================================
// D: deterministic child partial-sum + bias -> c0/c1. Thread = one (row,j);
// a row's 16 chunks are contiguous (4KB block, 256B stride). Grid = 768.
// ===========================================================================
__global__ __launch_bounds__(256)
void hc_child_reduce(const float* __restrict__ part2,
                     const float* __restrict__ b0,
                     const float* __restrict__ b1,
                     const int* __restrict__ pclass,
                     float* __restrict__ out_c0,
                     float* __restrict__ out_c1) {
    const int t   = blockIdx.x * 256 + threadIdx.x;   // 0 .. 4096*48-1
    const int row = t / NC_N;
    const int j   = t - row * NC_N;

    const float* prow = &part2[(size_t)row * (KC2 * PCH)];
    float lv[KC2];
    #pragma unroll
    for (int kc = 0; kc < KC2; ++kc) lv[kc] = prow[kc * PCH + j];
    float v = 0.f;
    #pragma unroll
    for (int kc = 0; kc < KC2; ++kc) v += lv[kc];

    const int c = pclass[row];
    if (j < C0_N)
        out_c0[(size_t)row * C0_N + j] = v + b0[c * C0_N + j];
    else
        out_c1[(size_t)row * C1_N + (j - C0_N)] = v + b1[c * C1_N + (j - C0_N)];
}

// ---------------------------------------------------------------------------
extern "C" void kernel_launch(void* const* d_in, const int* in_sizes, int n_in,
                              void* d_out, int out_size, void* d_ws, size_t ws_size,
                              hipStream_t stream) {
    const float* x  = (const float*)d_in[0];
    const float* pw = (const float*)d_in[1];
    const float* pb = (const float*)d_in[2];
    const float* w0 = (const float*)d_in[3];
    const float* b0 = (const float*)d_in[4];
    const float* w1 = (const float*)d_in[5];
    const float* b1 = (const float*)d_in[6];

    float* out_logits = (float*)d_out;                       // [4096][64]
    float* out_c0     = out_logits + (size_t)B_N * P_N;      // [4096][16]
    float* out_c1     = out_c0     + (size_t)B_N * C0_N;     // [4096][32]

    // ws: [counts 64] [pclass 4096] [lists 64*4096] [partials 16MB,
    // aliased by part2 16.8MB — partials fully consumed by B before C runs]
    int*   counts   = (int*)d_ws;
    int*   pclass   = counts + P_N;
    int*   lists    = pclass + B_N;
    float* partials = (float*)(lists + P_N * B_N);
    float* part2    = partials;

    hc_parent_partial<<<dim3(B_N / 64, KC1), 256, 0, stream>>>(
        x, pw, partials, counts);

    hc_parent_route<<<B_N / 4, 256, 0, stream>>>(
        partials, pb, x, pw, out_logits, counts, lists, pclass);

    hc_child_partial<<<dim3(P_N, KC2, 4), 256, 0, stream>>>(
        x, w0, w1, counts, lists, part2);

    hc_child_reduce<<<(B_N * NC_N) / 256, 256, 0, stream>>>(
        part2, b0, b1, pclass, out_c0, out_c1);
}

// Round 17
// 70.355 us; speedup vs baseline: 5.0179x; 5.0179x over previous
//
#include <hip/hip_runtime.h>
#include <hip/hip_bf16.h>

// Sizes fixed by the reference problem.
#define B_N   4096
#define D_N   1024
#define P_N   64
#define C0_N  16
#define C1_N  32
#define NC_N  48    // C0 + C1 concatenated

// parent GEMM K-split
#define KC1   16
#define DKC1  64
#define L1S   68     // 64+4: 16B-aligned rows; rows 16 apart -> 2-way bank alias (free)

// child GEMM K-split — KC2 MUST stay 8 (r14/r16: 16 gathered-row chunk
// writers per row -> ~30x HBM amplification regardless of line alignment).
#define KC2   8
#define DKC2  128
#define L2S   132    // 128+4 bank math
#define TR2   32     // r17: child row tile 64 -> 32 (2x blocks, 3/CU)
#define PCH   64     // part2 chunk padded 48 -> 64 floats (256B, line-aligned,
                     // single writer) — r15's proven-quiet write layout.

// Tie physics: fp32 softmax probs can only tie when the true logit gap is
// <~2e-7 (exp ulp 6e-8 near 1.0; prob ulp 1.9e-9 x s~64 = 1.2e-7; exp
// rounding +-6e-8). Our fp32 gap estimate is accurate to ~1e-9. tau=1e-6
// gives 5x margin and flags only ~15-30 rows total.
#define GAP_TAU 1e-6f
#define NEG_INF (-3.402823466e38f)

// Lessons (r10-r16): no grid.sync (~100us each); no per-block device fences
// (L2 writeback storm); no <500-block kernels (r12: 64 blocks = 87us); child
// partials: KC2=8 only (r14/r16 explosion); 256B single-writer write chunks.

// ===========================================================================
// A: parent-logit partials (proven since r9). Grid (64 tiles, 16 kc) = 1024
// blocks, 4/CU. Partials [row][kc][p]: 256B-aligned chunks (no sharing).
// Block (0,0) zeroes counts.
// ===========================================================================
__global__ __launch_bounds__(256, 4)
void hc_parent_partial(const float* __restrict__ x,
                       const float* __restrict__ pw,
                       float* __restrict__ partials,
                       int* __restrict__ counts) {
    __shared__ float xs[64 * L1S];
    __shared__ float ws[P_N * L1S];
    const int tid = threadIdx.x;
    if (blockIdx.x == 0 && blockIdx.y == 0 && tid < P_N) counts[tid] = 0;

    const int r0 = blockIdx.x * 64;
    const int d0 = blockIdx.y * DKC1;

    #pragma unroll
    for (int k = 0; k < 4; ++k) {        // x: 64 rows x 64 floats
        const int f = tid + 256 * k, r = f >> 4, dp = (f & 15) * 4;
        *(float4*)&xs[r * L1S + dp] =
            *(const float4*)&x[(size_t)(r0 + r) * D_N + d0 + dp];
    }
    #pragma unroll
    for (int k = 0; k < 4; ++k) {        // pw chunk: 64 rows x 64 floats
        const int f = tid + 256 * k, r = f >> 4, dp = (f & 15) * 4;
        *(float4*)&ws[r * L1S + dp] =
            *(const float4*)&pw[(size_t)r * D_N + d0 + dp];
    }
    __syncthreads();

    const int pt = tid & 15;
    const int rt = tid >> 4;
    float acc[4][4] = {};                // [i: parent][j: row]
    #pragma unroll
    for (int d = 0; d < DKC1; d += 4) {
        float4 w4[4], x4[4];
        #pragma unroll
        for (int i = 0; i < 4; ++i)
            w4[i] = *(const float4*)&ws[(pt + 16 * i) * L1S + d];
        #pragma unroll
        for (int j = 0; j < 4; ++j)
            x4[j] = *(const float4*)&xs[(rt + 16 * j) * L1S + d];
        #pragma unroll
        for (int i = 0; i < 4; ++i)
            #pragma unroll
            for (int j = 0; j < 4; ++j) {
                acc[i][j] += w4[i].x * x4[j].x;
                acc[i][j] += w4[i].y * x4[j].y;
                acc[i][j] += w4[i].z * x4[j].z;
                acc[i][j] += w4[i].w * x4[j].w;
            }
    }
    const int kcb = blockIdx.y;
    #pragma unroll
    for (int j = 0; j < 4; ++j) {
        const size_t rbase =
            (size_t)(r0 + rt + 16 * j) * (KC1 * P_N) + (size_t)kcb * P_N;
        #pragma unroll
        for (int i = 0; i < 4; ++i)
            partials[rbase + pt + 16 * i] = acc[i][j];
    }
}

// ===========================================================================
// B: route + block-local cooperative f64 fixup (proven r13). Block = 4 rows
// (wave = one row's 64 parents). Fast path: reduce + bias -> logits, top-2,
// bin. Near-ties -> LDS queue; then the whole block cooperatively emulates
// the reference's fp32 softmax in f64 (exp quantization near 1.0 ties
// near-equal logits; argmax takes the FIRST tied index). ~26/1024 blocks
// take the slow path.
// ===========================================================================
__global__ __launch_bounds__(256, 6)
void hc_parent_route(const float* __restrict__ partials,
                     const float* __restrict__ pb,
                     const float* __restrict__ x,
                     const float* __restrict__ pw,
                     float* __restrict__ out_logits,
                     int* __restrict__ counts,
                     int* __restrict__ lists,
                     int* __restrict__ pclass) {
    __shared__ double ld[P_N];
    __shared__ int    sq[8];
    __shared__ int    sqn;

    const int tid = threadIdx.x;
    const int p   = tid & 63;
    const int w   = tid >> 6;
    const int row = blockIdx.x * 4 + w;

    if (tid == 0) sqn = 0;

    // ---- fast path ----
    const float* prow = &partials[(size_t)row * (KC1 * P_N)];
    float lv[KC1];
    #pragma unroll
    for (int kc = 0; kc < KC1; ++kc) lv[kc] = prow[kc * P_N + p];
    float l = pb[p];
    #pragma unroll
    for (int kc = 0; kc < KC1; ++kc) l += lv[kc];

    out_logits[(size_t)row * P_N + p] = l;

    float m1 = l; int i1 = p; float m2 = NEG_INF;
    #pragma unroll
    for (int off = 32; off > 0; off >>= 1) {
        const float om1 = __shfl_xor(m1, off);
        const int   oi1 = __shfl_xor(i1, off);
        const float om2 = __shfl_xor(m2, off);
        if (om1 > m1 || (om1 == m1 && oi1 < i1)) {
            m2 = fmaxf(m1, om2); m1 = om1; i1 = oi1;
        } else m2 = fmaxf(m2, om1);
    }
    if (p == 0) {
        if (m1 - m2 > GAP_TAU) {
            const int pos = atomicAdd(&counts[i1], 1);
            lists[i1 * B_N + pos] = row;
            pclass[row] = i1;
        } else {
            const int q = atomicAdd(&sqn, 1);
            sq[q] = row;
        }
    }
    __syncthreads();

    const int nq = sqn;
    if (nq == 0) return;    // uniform: all threads past the barrier

    // ---- block-cooperative slow path (~26 blocks total take this) ----
    for (int qi = 0; qi < nq; ++qi) {
        const int srow = sq[qi];
        const float* xr = &x[(size_t)srow * D_N + p * 16];
        float4 xv[4];
        #pragma unroll
        for (int k = 0; k < 4; ++k) xv[k] = *(const float4*)&xr[k * 4];

        #pragma unroll 2
        for (int pass = 0; pass < 16; ++pass) {
            const int pp = w * 16 + pass;
            const float* wr = &pw[(size_t)pp * D_N + p * 16];
            double a0 = 0.0, a1 = 0.0, a2 = 0.0, a3 = 0.0;
            #pragma unroll
            for (int k = 0; k < 4; ++k) {
                const float4 wv = *(const float4*)&wr[k * 4];
                a0 = fma((double)wv.x, (double)xv[k].x, a0);
                a1 = fma((double)wv.y, (double)xv[k].y, a1);
                a2 = fma((double)wv.z, (double)xv[k].z, a2);
                a3 = fma((double)wv.w, (double)xv[k].w, a3);
            }
            double a = (a0 + a1) + (a2 + a3);
            #pragma unroll
            for (int off = 32; off > 0; off >>= 1) a += __shfl_xor(a, off);
            if (p == 0) ld[pp] = a;
        }
        __syncthreads();

        if (w == 0) {
            const double accv = (double)pb[p] + ld[p];
            const float  l32  = (float)accv;
            float m = l32;
            #pragma unroll
            for (int off = 32; off > 0; off >>= 1)
                m = fmaxf(m, __shfl_xor(m, off));
            const float e = (float)exp((double)(l32 - m));  // correctly-rounded
            double es = (double)e;
            #pragma unroll
            for (int off = 32; off > 0; off >>= 1) es += __shfl_xor(es, off);
            es = __shfl(es, 0);
            const float s    = (float)es;
            const float prob = e / s;    // IEEE f32 divide: ties survive
            float pm = prob; int pi = p;
            #pragma unroll
            for (int off = 32; off > 0; off >>= 1) {
                const float opm = __shfl_xor(pm, off);
                const int   opi = __shfl_xor(pi, off);
                if (opm > pm || (opm == pm && opi < pi)) { pm = opm; pi = opi; }
            }
            if (p == 0) {
                const int pos = atomicAdd(&counts[pi], 1);
                lists[pi * B_N + pos] = srow;
                pclass[srow] = pi;
            }
        }
        __syncthreads();
    }
}

// ===========================================================================
// C: child-GEMM partials. r17: 32-row tiles (was 64) -> ~1300 active blocks,
// LDS 42KB -> 3 blocks/CU. KC2=8 (mandatory), r15's quiet write layout:
// part2 [row][kc8][PCH=64], 256B single-writer chunks.
// Grid (64 classes, 8 kc, 8 tile-slots); ghost slots exit immediately.
// ===========================================================================
__global__ __launch_bounds__(256, 3)
void hc_child_partial(const float* __restrict__ x,
                      const float* __restrict__ w0,
                      const float* __restrict__ w1,
                      const int* __restrict__ counts,
                      const int* __restrict__ lists,
                      float* __restrict__ part2) {
    const int c  = blockIdx.x;
    const int kc = blockIdx.y;
    const int n  = counts[c];
    const int t0 = blockIdx.z * TR2;
    if (t0 >= n) return;
    const int m  = min(TR2, n - t0);
    const int d0 = kc * DKC2;

    __shared__ int   rl[TR2];
    __shared__ float xs[TR2 * L2S];
    __shared__ float ws[NC_N * L2S];

    const int tid = threadIdx.x;
    if (tid < TR2)
        rl[tid] = lists[c * B_N + t0 + (tid < m ? tid : 0)];

    // stage class's 48 child-weight rows: 1536 float4, 6 per thread
    #pragma unroll
    for (int k = 0; k < 6; ++k) {
        const int f = tid + 256 * k, j = f >> 5, dp = (f & 31) * 4;
        const float* src = (j < C0_N)
            ? &w0[((size_t)c * C0_N + j) * D_N + d0 + dp]
            : &w1[((size_t)c * C1_N + (j - C0_N)) * D_N + d0 + dp];
        *(float4*)&ws[j * L2S + dp] = *(const float4*)src;
    }
    __syncthreads();   // rl visible
    // stage gathered x rows: 32 x 128 = 1024 float4, 4 per thread
    #pragma unroll
    for (int k = 0; k < 4; ++k) {
        const int f = tid + 256 * k, r = f >> 5, dp = (f & 31) * 4;
        *(float4*)&xs[r * L2S + dp] =
            *(const float4*)&x[(size_t)rl[r] * D_N + d0 + dp];
    }
    __syncthreads();

    const int jt = tid & 15;
    const int rt = tid >> 4;

    float acc[3][2] = {};                // [i: output][j: row pair]
    #pragma unroll 2
    for (int d = 0; d < DKC2; d += 4) {
        float4 w4[3], x4[2];
        #pragma unroll
        for (int i = 0; i < 3; ++i)
            w4[i] = *(const float4*)&ws[(jt + 16 * i) * L2S + d];
        #pragma unroll
        for (int j = 0; j < 2; ++j)
            x4[j] = *(const float4*)&xs[(rt + 16 * j) * L2S + d];
        #pragma unroll
        for (int i = 0; i < 3; ++i)
            #pragma unroll
            for (int j = 0; j < 2; ++j) {
                acc[i][j] += w4[i].x * x4[j].x;
                acc[i][j] += w4[i].y * x4[j].y;
                acc[i][j] += w4[i].z * x4[j].z;
                acc[i][j] += w4[i].w * x4[j].w;
            }
    }

    #pragma unroll
    for (int j = 0; j < 2; ++j) {
        const int rr = rt + 16 * j;
        if (rr < m) {
            const size_t rbase =
                (size_t)rl[rr] * (KC2 * PCH) + (size_t)kc * PCH;
            #pragma unroll
            for (int i = 0; i < 4; ++i)   // i==3 writes padding (completes lines)
                part2[rbase + jt + 16 * i] = (i < 3) ? acc[i][j] : 0.0f;
        }
    }
}

// ===========================================================================
// D: deterministic child partial-sum + bias -> c0/c1. Thread = one (row,j);
// a row's 8 chunks are contiguous (2KB block, 256B stride). Grid = 768.
// ===========================================================================
__global__ __launch_bounds__(256)
void hc_child_reduce(const float* __restrict__ part2,
                     const float* __restrict__ b0,
                     const float* __restrict__ b1,
                     const int* __restrict__ pclass,
                     float* __restrict__ out_c0,
                     float* __restrict__ out_c1) {
    const int t   = blockIdx.x * 256 + threadIdx.x;   // 0 .. 4096*48-1
    const int row = t / NC_N;
    const int j   = t - row * NC_N;

    const float* prow = &part2[(size_t)row * (KC2 * PCH)];
    float lv[KC2];
    #pragma unroll
    for (int kc = 0; kc < KC2; ++kc) lv[kc] = prow[kc * PCH + j];
    float v = 0.f;
    #pragma unroll
    for (int kc = 0; kc < KC2; ++kc) v += lv[kc];

    const int c = pclass[row];
    if (j < C0_N)
        out_c0[(size_t)row * C0_N + j] = v + b0[c * C0_N + j];
    else
        out_c1[(size_t)row * C1_N + (j - C0_N)] = v + b1[c * C1_N + (j - C0_N)];
}

// ---------------------------------------------------------------------------
extern "C" void kernel_launch(void* const* d_in, const int* in_sizes, int n_in,
                              void* d_out, int out_size, void* d_ws, size_t ws_size,
                              hipStream_t stream) {
    const float* x  = (const float*)d_in[0];
    const float* pw = (const float*)d_in[1];
    const float* pb = (const float*)d_in[2];
    const float* w0 = (const float*)d_in[3];
    const float* b0 = (const float*)d_in[4];
    const float* w1 = (const float*)d_in[5];
    const float* b1 = (const float*)d_in[6];

    float* out_logits = (float*)d_out;                       // [4096][64]
    float* out_c0     = out_logits + (size_t)B_N * P_N;      // [4096][16]
    float* out_c1     = out_c0     + (size_t)B_N * C0_N;     // [4096][32]

    // ws: [counts 64] [pclass 4096] [lists 64*4096] [partials 16.8MB,
    // aliased by part2 8.4MB — partials fully consumed by B before C runs]
    int*   counts   = (int*)d_ws;
    int*   pclass   = counts + P_N;
    int*   lists    = pclass + B_N;
    float* partials = (float*)(lists + P_N * B_N);
    float* part2    = partials;

    hc_parent_partial<<<dim3(B_N / 64, KC1), 256, 0, stream>>>(
        x, pw, partials, counts);

    hc_parent_route<<<B_N / 4, 256, 0, stream>>>(
        partials, pb, x, pw, out_logits, counts, lists, pclass);

    hc_child_partial<<<dim3(P_N, KC2, 8), 256, 0, stream>>>(
        x, w0, w1, counts, lists, part2);

    hc_child_reduce<<<(B_N * NC_N) / 256, 256, 0, stream>>>(
        part2, b0, b1, pclass, out_c0, out_c1);
}